// Round 14
// baseline (238.329 us; speedup 1.0000x reference)
//
#include <hip/hip_runtime.h>
#include <math.h>

#define NB 8          // batch
#define NC 4          // sim channels
#define HW 802816     // 896*896
#define LMAX 16
#define TPB 256
#define NWAVE (TPB/64)
#define VEC 4
#define IPTV 4                  // vector iterations per thread
#define PXB (TPB*VEC*IPTV)      // 4096 pixels per block
#define BPB (HW/PXB)            // 196 blocks per batch (exact)
#define NSLOT 16                // replicated global accumulator slots

struct WS {
    float seg_ker[NSLOT][NB][LMAX];
    float seg_reg[NSLOT][NB][LMAX];
    float seg_n  [NSLOT][NB][LMAX];
    float seg_sim[NSLOT][NB][NC][LMAX];
    float dice   [NSLOT][6];
    int   kmax   [NSLOT][NB];
    float lagg;
};

__device__ __forceinline__ float waveReduceSum(float v) {
#pragma unroll
    for (int off = 32; off > 0; off >>= 1) v += __shfl_down(v, off, 64);
    return v;
}

#define REP9(M) M(1) M(2) M(3) M(4) M(5) M(6) M(7) M(8) M(9)

// ================= pass 1: labK/labR-keyed segment sums =================
// (TPB,4): compiler lands at VGPR=64 == the 8-waves/SIMD occupancy step (m69).
// Do NOT raise the cap: (TPB,2) -> VGPR 68 -> 4 waves/SIMD -> 82->99us (R13).
__global__ __launch_bounds__(TPB, 4) void pan_segs(
    const float* __restrict__ kerGT, const float* __restrict__ sims,
    const int* __restrict__ labK, const int* __restrict__ labR,
    WS* __restrict__ ws)
{
    const int b   = blockIdx.x / BPB;
    const int blk = blockIdx.x % BPB;
    const size_t pb = (size_t)b * HW;
    const int q0 = blk * PXB;
    const int lane = threadIdx.x & 63;
    const int wid  = threadIdx.x >> 6;
    const float* simsb = sims + (size_t)b * NC * HW;

    // 54 named float accumulators + 9 wave-uniform counters (scalar pipe)
#define DECL_ACC(l) float aK##l=0.f, aR##l=0.f, \
                          aS0_##l=0.f, aS1_##l=0.f, aS2_##l=0.f, aS3_##l=0.f; \
                    int cN##l = 0;
    REP9(DECL_ACC)
#undef DECL_ACC

#pragma unroll
    for (int i = 0; i < IPTV; ++i) {
        const int q = q0 + ((i*TPB + threadIdx.x) << 2);
        const size_t p = pb + q;
        const float4 kg4 = *(const float4*)(kerGT + p);
        const float4 sv0 = *(const float4*)(simsb + 0*HW + q);
        const float4 sv1 = *(const float4*)(simsb + 1*HW + q);
        const float4 sv2 = *(const float4*)(simsb + 2*HW + q);
        const float4 sv3 = *(const float4*)(simsb + 3*HW + q);
        const int4 lk4 = *(const int4*)(labK + p);
        const int4 lr4 = *(const int4*)(labR + p);

        const float kgA[VEC] = {kg4.x, kg4.y, kg4.z, kg4.w};
        const float s0A[VEC] = {sv0.x, sv0.y, sv0.z, sv0.w};
        const float s1A[VEC] = {sv1.x, sv1.y, sv1.z, sv1.w};
        const float s2A[VEC] = {sv2.x, sv2.y, sv2.z, sv2.w};
        const float s3A[VEC] = {sv3.x, sv3.y, sv3.z, sv3.w};
        const int lkA[VEC] = {lk4.x, lk4.y, lk4.z, lk4.w};
        const int lrA[VEC] = {lr4.x, lr4.y, lr4.z, lr4.w};

#pragma unroll
        for (int j = 0; j < VEC; ++j) {
            const float kg = kgA[j];
            const int lk = lkA[j];
            const int lr = lrA[j];
            const float v0 = s0A[j], v1 = s1A[j], v2 = s2A[j], v3 = s3A[j];
#define UPDK(l) { \
            cN##l += (int)__popcll(__ballot(lk == l)); \
            const float fk = (lk == l) ? 1.f : 0.f; \
            aK##l   = fmaf(fk, kg, aK##l); \
            aS0_##l = fmaf(fk, v0, aS0_##l); \
            aS1_##l = fmaf(fk, v1, aS1_##l); \
            aS2_##l = fmaf(fk, v2, aS2_##l); \
            aS3_##l = fmaf(fk, v3, aS3_##l); \
            const float fr = (lr == l) ? 1.f : 0.f; \
            aR##l   = fmaf(fr, kg, aR##l); }
            REP9(UPDK)
#undef UPDK
        }
    }

    // ---- flush: 54 wave shfl-reduces + counts, block-reduce in LDS ----
    __shared__ float s_part[NWAVE][63];
    __shared__ int   s_km[NWAVE];

#define WFLUSH(l) { \
    float r; \
    r = waveReduceSum(aK##l);   if (lane==0) s_part[wid][ 0 + (l-1)] = r; \
    r = waveReduceSum(aR##l);   if (lane==0) s_part[wid][ 9 + (l-1)] = r; \
    r = waveReduceSum(aS0_##l); if (lane==0) s_part[wid][18 + (l-1)] = r; \
    r = waveReduceSum(aS1_##l); if (lane==0) s_part[wid][27 + (l-1)] = r; \
    r = waveReduceSum(aS2_##l); if (lane==0) s_part[wid][36 + (l-1)] = r; \
    r = waveReduceSum(aS3_##l); if (lane==0) s_part[wid][45 + (l-1)] = r; \
    if (lane==0) s_part[wid][54 + (l-1)] = (float)cN##l; }
    REP9(WFLUSH)
#undef WFLUSH

    int km = 0;
#define KMCHK(l) if (cN##l) km = l;
    REP9(KMCHK)
#undef KMCHK
    if (lane == 0) s_km[wid] = km;
    __syncthreads();

    const int slot = blockIdx.x & (NSLOT-1);
    if (threadIdx.x < 63) {
        const int t = threadIdx.x;
        const float s = s_part[0][t] + s_part[1][t] + s_part[2][t] + s_part[3][t];
        float* dst;
        if      (t <  9) dst = &ws->seg_ker[slot][b][t + 1];
        else if (t < 18) dst = &ws->seg_reg[slot][b][t - 9 + 1];
        else if (t < 54) { const int u = t - 18; dst = &ws->seg_sim[slot][b][u/9][(u%9) + 1]; }
        else             dst = &ws->seg_n[slot][b][t - 54 + 1];
        unsafeAtomicAdd(dst, s);
    } else if (threadIdx.x == 63) {
        const int m = max(max(s_km[0], s_km[1]), max(s_km[2], s_km[3]));
        atomicMax(&ws->kmax[slot][b], m);
    }
}

// ================= pass 2: dice + aggregation loss =================
__global__ __launch_bounds__(TPB, 4) void pan_pass2(
    const float* __restrict__ predR, const float* __restrict__ regGT,
    const float* __restrict__ predK, const float* __restrict__ kerGT,
    const float* __restrict__ sims,  const int* __restrict__ labR,
    const int* __restrict__ labK, WS* __restrict__ ws)
{
    const int b   = blockIdx.x / BPB;
    const int blk = blockIdx.x % BPB;
    const size_t pb = (size_t)b * HW;
    const int q0 = blk * PXB;
    const int lane = threadIdx.x & 63;
    const int wid  = threadIdx.x >> 6;
    const float* simsb = sims + (size_t)b * NC * HW;

    __shared__ float s_ker[LMAX], s_reg[LMAX], s_sim[NC][LMAX];
    __shared__ float s_part[NWAVE][7];
    if (threadIdx.x < LMAX) {
        const int l = threadIdx.x;
        float k=0.f, r=0.f, c0=0.f, c1=0.f, c2=0.f, c3=0.f;
#pragma unroll
        for (int s = 0; s < NSLOT; ++s) {
            k  += ws->seg_ker[s][b][l];
            r  += ws->seg_reg[s][b][l];
            c0 += ws->seg_sim[s][b][0][l];
            c1 += ws->seg_sim[s][b][1][l];
            c2 += ws->seg_sim[s][b][2][l];
            c3 += ws->seg_sim[s][b][3][l];
        }
        s_ker[l]=k; s_reg[l]=r; s_sim[0][l]=c0; s_sim[1][l]=c1; s_sim[2][l]=c2; s_sim[3][l]=c3;
    }
    __syncthreads();

    float d0=0.f,d1=0.f,d2=0.f,d3=0.f,d4=0.f,d5=0.f;
    float acc = 0.f;
#pragma unroll
    for (int i = 0; i < IPTV; ++i) {
        const int q = q0 + ((i*TPB + threadIdx.x) << 2);
        const size_t p = pb + q;
        const float4 pr4 = *(const float4*)(predR + p);
        const float4 rg4 = *(const float4*)(regGT + p);
        const float4 pk4 = *(const float4*)(predK + p);
        const float4 kg4 = *(const float4*)(kerGT + p);
        const float4 sv0 = *(const float4*)(simsb + 0*HW + q);
        const float4 sv1 = *(const float4*)(simsb + 1*HW + q);
        const float4 sv2 = *(const float4*)(simsb + 2*HW + q);
        const float4 sv3 = *(const float4*)(simsb + 3*HW + q);
        const int4 lk4 = *(const int4*)(labK + p);
        const int4 lr4 = *(const int4*)(labR + p);

        const float prA[VEC] = {pr4.x, pr4.y, pr4.z, pr4.w};
        const float rgA[VEC] = {rg4.x, rg4.y, rg4.z, rg4.w};
        const float pkA[VEC] = {pk4.x, pk4.y, pk4.z, pk4.w};
        const float kgA[VEC] = {kg4.x, kg4.y, kg4.z, kg4.w};
        const float smA[NC][VEC] = {{sv0.x,sv0.y,sv0.z,sv0.w},{sv1.x,sv1.y,sv1.z,sv1.w},
                                    {sv2.x,sv2.y,sv2.z,sv2.w},{sv3.x,sv3.y,sv3.z,sv3.w}};
        const int lkA[VEC] = {lk4.x, lk4.y, lk4.z, lk4.w};
        const int lrA[VEC] = {lr4.x, lr4.y, lr4.z, lr4.w};

#pragma unroll
        for (int j = 0; j < VEC; ++j) {
            const float rg = rgA[j], kg = kgA[j];
            const float sr = 1.f / (1.f + __expf(-prA[j]));
            const float sk = 1.f / (1.f + __expf(-pkA[j]));
            const float prm = sr * rg;
            const float rgm = rg * rg;
            d0 += prm * rgm; d1 += prm; d2 += rgm;
            d3 += sk * kg;   d4 += sk;  d5 += kg;

            const int lk = lkA[j] & (LMAX-1);
            const int lr = lrA[j] & (LMAX-1);
            const float ck = (lk > 0) ? s_ker[lk] : 0.f;
            const float cr = (lr > 0) ? s_reg[lr] : 0.f;
            const float inv = 1.f / (ck + 1.f);
            float sq = 0.f;
#pragma unroll
            for (int c = 0; c < NC; ++c) {
                const float Fp = smA[c][j] * rg;
                const float G  = (lk > 0) ? s_sim[c][lk] * inv : 0.f;
                const float d  = Fp - G;
                sq += d * d;
            }
            float nr = (sq > 0.f) ? sqrtf(sq) : 0.f;
            nr -= 0.5f;
            nr  = fmaxf(nr, 0.f);
            acc += __logf(nr*nr + 1.f) / (cr + 1.f);
        }
    }

    d0 = waveReduceSum(d0); d1 = waveReduceSum(d1); d2 = waveReduceSum(d2);
    d3 = waveReduceSum(d3); d4 = waveReduceSum(d4); d5 = waveReduceSum(d5);
    acc = waveReduceSum(acc);
    if (lane == 0) {
        s_part[wid][0]=d0; s_part[wid][1]=d1; s_part[wid][2]=d2;
        s_part[wid][3]=d3; s_part[wid][4]=d4; s_part[wid][5]=d5;
        s_part[wid][6]=acc;
    }
    __syncthreads();
    const int slot = blockIdx.x & (NSLOT-1);
    if (threadIdx.x < 7) {
        const int t = threadIdx.x;
        const float s = s_part[0][t] + s_part[1][t] + s_part[2][t] + s_part[3][t];
        if (t < 6) unsafeAtomicAdd(&ws->dice[slot][t], s);
        else       unsafeAtomicAdd(&ws->lagg, s);
    }
}

__global__ void pan_finalize(const WS* __restrict__ ws, float* __restrict__ out)
{
    if (threadIdx.x != 0 || blockIdx.x != 0) return;
    const double f0 = log(10.0);
    double Ldis = 0.0;
    int kmaxb[NB];
    for (int b = 0; b < NB; ++b) {
        int m = 0;
        for (int s = 0; s < NSLOT; ++s) m = max(m, ws->kmax[s][b]);
        kmaxb[b] = m;
    }
    for (int b = 0; b < NB; ++b) {
        const int K = kmaxb[b];
        if (K >= 2) {
            double t1 = 0.0;
            const int lim = (K < LMAX-1) ? K : (LMAX-1);
            for (int l = 1; l <= lim; ++l) {
                float sqS = 0.f;
                for (int c = 0; c < NC; ++c) {
                    float S = 0.f;
                    for (int s = 0; s < NSLOT; ++s) S += ws->seg_sim[s][b][c][l];
                    sqS += S * S;
                }
                float n_l = 0.f;
                for (int s = 0; s < NSLOT; ++s) n_l += ws->seg_n[s][b][l];
                const float nm  = (sqS > 0.f) ? sqrtf(sqS) : 0.f;
                float gap = 3.0f - nm;
                gap = fmaxf(gap, 0.f);
                const double f = log((double)gap*gap + 1.0);
                t1 += (double)n_l * (f - f0);
            }
            Ldis += (K - 1.0) * t1
                  + (double)K * (K - 1) * 0.5 * (double)NB * (double)HW * f0;
        }
    }
    double dice[6];
    for (int j = 0; j < 6; ++j) {
        double s = 0.0;
        for (int sl = 0; sl < NSLOT; ++sl) s += ws->dice[sl][j];
        dice[j] = s;
    }
    const double numk = (double)kmaxb[NB-1];
    const double Lagg = (double)ws->lagg / numk;
    const double lr = 1.0 - (2.0*dice[0] + 1e-6) / (dice[1] + dice[2] + 1e-6);
    const double lk = 1.0 - (2.0*dice[3] + 1e-6) / (dice[4] + dice[5] + 1e-6);
    out[0] = (float)(lr + 0.5*lk + 0.25*(Lagg + Ldis));
}

extern "C" void kernel_launch(void* const* d_in, const int* in_sizes, int n_in,
                              void* d_out, int out_size, void* d_ws, size_t ws_size,
                              hipStream_t stream)
{
    const float* predR = (const float*)d_in[0];
    const float* regGT = (const float*)d_in[1];
    const float* predK = (const float*)d_in[2];
    const float* kerGT = (const float*)d_in[3];
    const float* sims  = (const float*)d_in[4];
    const int*   labR  = (const int*)d_in[5];
    const int*   labK  = (const int*)d_in[6];
    WS* ws = (WS*)d_ws;

    hipMemsetAsync(d_ws, 0, sizeof(WS), stream);

    pan_segs <<<dim3(NB * BPB), dim3(TPB), 0, stream>>>(kerGT, sims, labK, labR, ws);
    pan_pass2<<<dim3(NB * BPB), dim3(TPB), 0, stream>>>(predR, regGT, predK, kerGT, sims, labR, labK, ws);
    pan_finalize<<<1, 64, 0, stream>>>(ws, (float*)d_out);
}

// Round 15
// 176.871 us; speedup vs baseline: 1.3475x; 1.3475x over previous
//
#include <hip/hip_runtime.h>
#include <math.h>

#define NB 8          // batch
#define NC 4          // sim channels
#define HW 802816     // 896*896
#define LMAX 16
#define TPB 256
#define NWAVE (TPB/64)
#define VEC 4
#define IPTV 4                  // vector iterations per thread
#define PXB (TPB*VEC*IPTV)      // 4096 pixels per block
#define BPB (HW/PXB)            // 196 blocks per batch (exact)
#define NSLOT 16                // replicated global accumulator slots

struct WS {
    float seg_ker[NSLOT][NB][LMAX];
    float seg_reg[NSLOT][NB][LMAX];
    float seg_n  [NSLOT][NB][LMAX];
    float seg_sim[NSLOT][NB][NC][LMAX];
    float dice   [NSLOT][6];
    int   kmax   [NSLOT][NB];
    float lagg;
};

__device__ __forceinline__ float waveReduceSum(float v) {
#pragma unroll
    for (int off = 32; off > 0; off >>= 1) v += __shfl_down(v, off, 64);
    return v;
}

#define REP9(M) M(1) M(2) M(3) M(4) M(5) M(6) M(7) M(8) M(9)

// ================= pass 1: labK/labR-keyed segment sums =================
// (TPB,4): compiler lands at VGPR=64 == the 8-waves/SIMD occupancy step (m69).
// Do NOT raise the cap here: (TPB,2) -> VGPR 68 -> 4 waves/SIMD -> 82->99us (R13).
__global__ __launch_bounds__(TPB, 4) void pan_segs(
    const float* __restrict__ kerGT, const float* __restrict__ sims,
    const int* __restrict__ labK, const int* __restrict__ labR,
    WS* __restrict__ ws)
{
    const int b   = blockIdx.x / BPB;
    const int blk = blockIdx.x % BPB;
    const size_t pb = (size_t)b * HW;
    const int q0 = blk * PXB;
    const int lane = threadIdx.x & 63;
    const int wid  = threadIdx.x >> 6;
    const float* simsb = sims + (size_t)b * NC * HW;

    // 54 named float accumulators + 9 wave-uniform counters (scalar pipe)
#define DECL_ACC(l) float aK##l=0.f, aR##l=0.f, \
                          aS0_##l=0.f, aS1_##l=0.f, aS2_##l=0.f, aS3_##l=0.f; \
                    int cN##l = 0;
    REP9(DECL_ACC)
#undef DECL_ACC

#pragma unroll
    for (int i = 0; i < IPTV; ++i) {
        const int q = q0 + ((i*TPB + threadIdx.x) << 2);
        const size_t p = pb + q;
        const float4 kg4 = *(const float4*)(kerGT + p);
        const float4 sv0 = *(const float4*)(simsb + 0*HW + q);
        const float4 sv1 = *(const float4*)(simsb + 1*HW + q);
        const float4 sv2 = *(const float4*)(simsb + 2*HW + q);
        const float4 sv3 = *(const float4*)(simsb + 3*HW + q);
        const int4 lk4 = *(const int4*)(labK + p);
        const int4 lr4 = *(const int4*)(labR + p);

        const float kgA[VEC] = {kg4.x, kg4.y, kg4.z, kg4.w};
        const float s0A[VEC] = {sv0.x, sv0.y, sv0.z, sv0.w};
        const float s1A[VEC] = {sv1.x, sv1.y, sv1.z, sv1.w};
        const float s2A[VEC] = {sv2.x, sv2.y, sv2.z, sv2.w};
        const float s3A[VEC] = {sv3.x, sv3.y, sv3.z, sv3.w};
        const int lkA[VEC] = {lk4.x, lk4.y, lk4.z, lk4.w};
        const int lrA[VEC] = {lr4.x, lr4.y, lr4.z, lr4.w};

#pragma unroll
        for (int j = 0; j < VEC; ++j) {
            const float kg = kgA[j];
            const int lk = lkA[j];
            const int lr = lrA[j];
            const float v0 = s0A[j], v1 = s1A[j], v2 = s2A[j], v3 = s3A[j];
#define UPDK(l) { \
            cN##l += (int)__popcll(__ballot(lk == l)); \
            const float fk = (lk == l) ? 1.f : 0.f; \
            aK##l   = fmaf(fk, kg, aK##l); \
            aS0_##l = fmaf(fk, v0, aS0_##l); \
            aS1_##l = fmaf(fk, v1, aS1_##l); \
            aS2_##l = fmaf(fk, v2, aS2_##l); \
            aS3_##l = fmaf(fk, v3, aS3_##l); \
            const float fr = (lr == l) ? 1.f : 0.f; \
            aR##l   = fmaf(fr, kg, aR##l); }
            REP9(UPDK)
#undef UPDK
        }
    }

    // ---- flush: 54 wave shfl-reduces + counts, block-reduce in LDS ----
    __shared__ float s_part[NWAVE][63];
    __shared__ int   s_km[NWAVE];

#define WFLUSH(l) { \
    float r; \
    r = waveReduceSum(aK##l);   if (lane==0) s_part[wid][ 0 + (l-1)] = r; \
    r = waveReduceSum(aR##l);   if (lane==0) s_part[wid][ 9 + (l-1)] = r; \
    r = waveReduceSum(aS0_##l); if (lane==0) s_part[wid][18 + (l-1)] = r; \
    r = waveReduceSum(aS1_##l); if (lane==0) s_part[wid][27 + (l-1)] = r; \
    r = waveReduceSum(aS2_##l); if (lane==0) s_part[wid][36 + (l-1)] = r; \
    r = waveReduceSum(aS3_##l); if (lane==0) s_part[wid][45 + (l-1)] = r; \
    if (lane==0) s_part[wid][54 + (l-1)] = (float)cN##l; }
    REP9(WFLUSH)
#undef WFLUSH

    int km = 0;
#define KMCHK(l) if (cN##l) km = l;
    REP9(KMCHK)
#undef KMCHK
    if (lane == 0) s_km[wid] = km;
    __syncthreads();

    const int slot = blockIdx.x & (NSLOT-1);
    if (threadIdx.x < 63) {
        const int t = threadIdx.x;
        const float s = s_part[0][t] + s_part[1][t] + s_part[2][t] + s_part[3][t];
        float* dst;
        if      (t <  9) dst = &ws->seg_ker[slot][b][t + 1];
        else if (t < 18) dst = &ws->seg_reg[slot][b][t - 9 + 1];
        else if (t < 54) { const int u = t - 18; dst = &ws->seg_sim[slot][b][u/9][(u%9) + 1]; }
        else             dst = &ws->seg_n[slot][b][t - 54 + 1];
        unsafeAtomicAdd(dst, s);
    } else if (threadIdx.x == 63) {
        const int m = max(max(s_km[0], s_km[1]), max(s_km[2], s_km[3]));
        atomicMax(&ws->kmax[slot][b], m);
    }
}

// ================= pass 2: dice + aggregation loss =================
// Bare __launch_bounds__(TPB): compiler picks ~84-100 VGPR for this 10-stream
// loop. Pinning it to (TPB,4) costs +24us (R14) -- opposite trade vs pan_segs.
__global__ __launch_bounds__(TPB) void pan_pass2(
    const float* __restrict__ predR, const float* __restrict__ regGT,
    const float* __restrict__ predK, const float* __restrict__ kerGT,
    const float* __restrict__ sims,  const int* __restrict__ labR,
    const int* __restrict__ labK, WS* __restrict__ ws)
{
    const int b   = blockIdx.x / BPB;
    const int blk = blockIdx.x % BPB;
    const size_t pb = (size_t)b * HW;
    const int q0 = blk * PXB;
    const int lane = threadIdx.x & 63;
    const int wid  = threadIdx.x >> 6;
    const float* simsb = sims + (size_t)b * NC * HW;

    __shared__ float s_ker[LMAX], s_reg[LMAX], s_sim[NC][LMAX];
    __shared__ float s_part[NWAVE][7];
    if (threadIdx.x < LMAX) {
        const int l = threadIdx.x;
        float k=0.f, r=0.f, c0=0.f, c1=0.f, c2=0.f, c3=0.f;
#pragma unroll
        for (int s = 0; s < NSLOT; ++s) {
            k  += ws->seg_ker[s][b][l];
            r  += ws->seg_reg[s][b][l];
            c0 += ws->seg_sim[s][b][0][l];
            c1 += ws->seg_sim[s][b][1][l];
            c2 += ws->seg_sim[s][b][2][l];
            c3 += ws->seg_sim[s][b][3][l];
        }
        s_ker[l]=k; s_reg[l]=r; s_sim[0][l]=c0; s_sim[1][l]=c1; s_sim[2][l]=c2; s_sim[3][l]=c3;
    }
    __syncthreads();

    float d0=0.f,d1=0.f,d2=0.f,d3=0.f,d4=0.f,d5=0.f;
    float acc = 0.f;
#pragma unroll
    for (int i = 0; i < IPTV; ++i) {
        const int q = q0 + ((i*TPB + threadIdx.x) << 2);
        const size_t p = pb + q;
        const float4 pr4 = *(const float4*)(predR + p);
        const float4 rg4 = *(const float4*)(regGT + p);
        const float4 pk4 = *(const float4*)(predK + p);
        const float4 kg4 = *(const float4*)(kerGT + p);
        const float4 sv0 = *(const float4*)(simsb + 0*HW + q);
        const float4 sv1 = *(const float4*)(simsb + 1*HW + q);
        const float4 sv2 = *(const float4*)(simsb + 2*HW + q);
        const float4 sv3 = *(const float4*)(simsb + 3*HW + q);
        const int4 lk4 = *(const int4*)(labK + p);
        const int4 lr4 = *(const int4*)(labR + p);

        const float prA[VEC] = {pr4.x, pr4.y, pr4.z, pr4.w};
        const float rgA[VEC] = {rg4.x, rg4.y, rg4.z, rg4.w};
        const float pkA[VEC] = {pk4.x, pk4.y, pk4.z, pk4.w};
        const float kgA[VEC] = {kg4.x, kg4.y, kg4.z, kg4.w};
        const float smA[NC][VEC] = {{sv0.x,sv0.y,sv0.z,sv0.w},{sv1.x,sv1.y,sv1.z,sv1.w},
                                    {sv2.x,sv2.y,sv2.z,sv2.w},{sv3.x,sv3.y,sv3.z,sv3.w}};
        const int lkA[VEC] = {lk4.x, lk4.y, lk4.z, lk4.w};
        const int lrA[VEC] = {lr4.x, lr4.y, lr4.z, lr4.w};

#pragma unroll
        for (int j = 0; j < VEC; ++j) {
            const float rg = rgA[j], kg = kgA[j];
            const float sr = 1.f / (1.f + __expf(-prA[j]));
            const float sk = 1.f / (1.f + __expf(-pkA[j]));
            const float prm = sr * rg;
            const float rgm = rg * rg;
            d0 += prm * rgm; d1 += prm; d2 += rgm;
            d3 += sk * kg;   d4 += sk;  d5 += kg;

            const int lk = lkA[j] & (LMAX-1);
            const int lr = lrA[j] & (LMAX-1);
            const float ck = (lk > 0) ? s_ker[lk] : 0.f;
            const float cr = (lr > 0) ? s_reg[lr] : 0.f;
            const float inv = 1.f / (ck + 1.f);
            float sq = 0.f;
#pragma unroll
            for (int c = 0; c < NC; ++c) {
                const float Fp = smA[c][j] * rg;
                const float G  = (lk > 0) ? s_sim[c][lk] * inv : 0.f;
                const float d  = Fp - G;
                sq += d * d;
            }
            float nr = (sq > 0.f) ? sqrtf(sq) : 0.f;
            nr -= 0.5f;
            nr  = fmaxf(nr, 0.f);
            acc += __logf(nr*nr + 1.f) / (cr + 1.f);
        }
    }

    d0 = waveReduceSum(d0); d1 = waveReduceSum(d1); d2 = waveReduceSum(d2);
    d3 = waveReduceSum(d3); d4 = waveReduceSum(d4); d5 = waveReduceSum(d5);
    acc = waveReduceSum(acc);
    if (lane == 0) {
        s_part[wid][0]=d0; s_part[wid][1]=d1; s_part[wid][2]=d2;
        s_part[wid][3]=d3; s_part[wid][4]=d4; s_part[wid][5]=d5;
        s_part[wid][6]=acc;
    }
    __syncthreads();
    const int slot = blockIdx.x & (NSLOT-1);
    if (threadIdx.x < 7) {
        const int t = threadIdx.x;
        const float s = s_part[0][t] + s_part[1][t] + s_part[2][t] + s_part[3][t];
        if (t < 6) unsafeAtomicAdd(&ws->dice[slot][t], s);
        else       unsafeAtomicAdd(&ws->lagg, s);
    }
}

__global__ void pan_finalize(const WS* __restrict__ ws, float* __restrict__ out)
{
    if (threadIdx.x != 0 || blockIdx.x != 0) return;
    const double f0 = log(10.0);
    double Ldis = 0.0;
    int kmaxb[NB];
    for (int b = 0; b < NB; ++b) {
        int m = 0;
        for (int s = 0; s < NSLOT; ++s) m = max(m, ws->kmax[s][b]);
        kmaxb[b] = m;
    }
    for (int b = 0; b < NB; ++b) {
        const int K = kmaxb[b];
        if (K >= 2) {
            double t1 = 0.0;
            const int lim = (K < LMAX-1) ? K : (LMAX-1);
            for (int l = 1; l <= lim; ++l) {
                float sqS = 0.f;
                for (int c = 0; c < NC; ++c) {
                    float S = 0.f;
                    for (int s = 0; s < NSLOT; ++s) S += ws->seg_sim[s][b][c][l];
                    sqS += S * S;
                }
                float n_l = 0.f;
                for (int s = 0; s < NSLOT; ++s) n_l += ws->seg_n[s][b][l];
                const float nm  = (sqS > 0.f) ? sqrtf(sqS) : 0.f;
                float gap = 3.0f - nm;
                gap = fmaxf(gap, 0.f);
                const double f = log((double)gap*gap + 1.0);
                t1 += (double)n_l * (f - f0);
            }
            Ldis += (K - 1.0) * t1
                  + (double)K * (K - 1) * 0.5 * (double)NB * (double)HW * f0;
        }
    }
    double dice[6];
    for (int j = 0; j < 6; ++j) {
        double s = 0.0;
        for (int sl = 0; sl < NSLOT; ++sl) s += ws->dice[sl][j];
        dice[j] = s;
    }
    const double numk = (double)kmaxb[NB-1];
    const double Lagg = (double)ws->lagg / numk;
    const double lr = 1.0 - (2.0*dice[0] + 1e-6) / (dice[1] + dice[2] + 1e-6);
    const double lk = 1.0 - (2.0*dice[3] + 1e-6) / (dice[4] + dice[5] + 1e-6);
    out[0] = (float)(lr + 0.5*lk + 0.25*(Lagg + Ldis));
}

extern "C" void kernel_launch(void* const* d_in, const int* in_sizes, int n_in,
                              void* d_out, int out_size, void* d_ws, size_t ws_size,
                              hipStream_t stream)
{
    const float* predR = (const float*)d_in[0];
    const float* regGT = (const float*)d_in[1];
    const float* predK = (const float*)d_in[2];
    const float* kerGT = (const float*)d_in[3];
    const float* sims  = (const float*)d_in[4];
    const int*   labR  = (const int*)d_in[5];
    const int*   labK  = (const int*)d_in[6];
    WS* ws = (WS*)d_ws;

    hipMemsetAsync(d_ws, 0, sizeof(WS), stream);

    pan_segs <<<dim3(NB * BPB), dim3(TPB), 0, stream>>>(kerGT, sims, labK, labR, ws);
    pan_pass2<<<dim3(NB * BPB), dim3(TPB), 0, stream>>>(predR, regGT, predK, kerGT, sims, labR, labK, ws);
    pan_finalize<<<1, 64, 0, stream>>>(ws, (float*)d_out);
}